// Round 10
// baseline (58.725 us; speedup 1.0000x reference)
//
#include <hip/hip_runtime.h>
#include <stdint.h>

#define K_DIM 1024
#define M_TOT 16384
#define BM 128
#define BN 128
#define BK 64

typedef __attribute__((ext_vector_type(8))) short bf16x8;
typedef __attribute__((ext_vector_type(4))) float f32x4;
typedef __attribute__((ext_vector_type(8))) unsigned short u16x8;

__device__ inline uint16_t f2bf(float f) {
    union { float f; uint32_t u; } v; v.f = f;
    return (uint16_t)((v.u + 0x7fffu + ((v.u >> 16) & 1u)) >> 16);
}

// ---- x (16M f32) -> bf16 (only used by the 2048 fallback path) ----
__global__ void cvt_x_kernel(const float* __restrict__ x, uint16_t* __restrict__ xb) {
    const size_t n8 = (size_t)M_TOT * K_DIM / 8;
    for (size_t i = (size_t)blockIdx.x * blockDim.x + threadIdx.x; i < n8;
         i += (size_t)gridDim.x * blockDim.x) {
        const float4* s = (const float4*)x + i * 2;
        float4 a = s[0], b = s[1];
        u16x8 v;
        v[0] = f2bf(a.x); v[1] = f2bf(a.y); v[2] = f2bf(a.z); v[3] = f2bf(a.w);
        v[4] = f2bf(b.x); v[5] = f2bf(b.y); v[6] = f2bf(b.z); v[7] = f2bf(b.w);
        *(u16x8*)(xb + i * 8) = v;
    }
}

// ---- real-only weights: Wc[k][s] = cos(2*pi*k*s/N), bf16 [1024][1024] ----
__global__ void build_wc_kernel(const float* __restrict__ wcos, uint16_t* __restrict__ W) {
    int i = blockIdx.x * blockDim.x + threadIdx.x;
    int k = i >> 7;
    int sc = (i & 127) * 8;
    const float4* c = (const float4*)(wcos + (size_t)k * K_DIM + sc);
    float4 c0 = c[0], c1 = c[1];
    u16x8 vc;
    vc[0] = f2bf(c0.x); vc[1] = f2bf(c0.y); vc[2] = f2bf(c0.z); vc[3] = f2bf(c0.w);
    vc[4] = f2bf(c1.x); vc[5] = f2bf(c1.y); vc[6] = f2bf(c1.z); vc[7] = f2bf(c1.w);
    *(u16x8*)(W + (size_t)k * K_DIM + sc) = vc;
}

// ---- interleaved weights (fallback path): W[2k][s]=cos, W[2k+1][s]=-sin ----
__global__ void build_w_kernel(const float* __restrict__ wsin, const float* __restrict__ wcos,
                               uint16_t* __restrict__ W) {
    int i = blockIdx.x * blockDim.x + threadIdx.x;
    int k = i >> 7;
    int sc = (i & 127) * 8;
    const float4* c = (const float4*)(wcos + (size_t)k * K_DIM + sc);
    const float4* s = (const float4*)(wsin + (size_t)k * K_DIM + sc);
    float4 c0 = c[0], c1 = c[1], s0 = s[0], s1 = s[1];
    u16x8 vc, vs;
    vc[0] = f2bf(c0.x); vc[1] = f2bf(c0.y); vc[2] = f2bf(c0.z); vc[3] = f2bf(c0.w);
    vc[4] = f2bf(c1.x); vc[5] = f2bf(c1.y); vc[6] = f2bf(c1.z); vc[7] = f2bf(c1.w);
    vs[0] = f2bf(-s0.x); vs[1] = f2bf(-s0.y); vs[2] = f2bf(-s0.z); vs[3] = f2bf(-s0.w);
    vs[4] = f2bf(-s1.x); vs[5] = f2bf(-s1.y); vs[6] = f2bf(-s1.z); vs[7] = f2bf(-s1.w);
    *(u16x8*)(W + (size_t)(2 * k) * K_DIM + sc) = vc;
    *(u16x8*)(W + (size_t)(2 * k + 1) * K_DIM + sc) = vs;
}

// =====================================================================
// Fused-cvt 128x128 / BK=32 bf16 MFMA GEMM — OCCUPANCY variant:
//   LDS = 32 KiB (2 dbuf x [A 128x32 + B 128x32] bf16) -> 4 blocks/CU,
//   16 waves/CU (4/SIMD): independent blocks fill each other's stalls.
//   A: reg-staged f32 (issued 1 tile ahead) -> cvt_pk -> swizzled ds_write.
//   B: global_load_lds, pre-swizzled source, linear LDS dest.
//   Swizzle for 64-B rows: slot ^= (row & 3)  (both sides; bank-uniform).
//   One barrier per K-tile; boundary vmcnt(4) drains only B(kt+1).
// =====================================================================
template <int NDIM>
__global__ __launch_bounds__(256, 4) void dft_gemm128f(const float* __restrict__ X,
                                                       const uint16_t* __restrict__ Bw,
                                                       float* __restrict__ C,
                                                       long long out_elems) {
    constexpr int BMt = 128, BKt = 32;
    constexpr int NT = NDIM / 128;        // n-tiles (8)
    constexpr int NKT = K_DIM / BKt;      // 32 K-tiles
    __shared__ uint16_t lds[2][2][BMt * BKt];   // [dbuf][A=0/B=1][128*32]

    const int t = threadIdx.x;
    const int l = t & 63;
    const int w = t >> 6;                 // 0..3
    const int wm = (w >> 1) * 64;
    const int wn = (w & 1) * 64;
    const int lr = l & 15;
    const int lhi = l >> 4;               // 0..3
    const int xr3 = lr & 3;

    // T1: bijective XCD swizzle (nwg = 1024, %8==0). q=128 -> the 8 bn-blocks
    // sharing an A panel land in one XCD (A reuse via L2).
    int bid = blockIdx.x;
    {
        int nwg = gridDim.x;
        if ((nwg & 7) == 0) { int q = nwg >> 3; bid = (bid & 7) * q + (bid >> 3); }
    }
    const int bm = (bid / NT) * BMt;
    const int bn = (bid % NT) * 128;

    // staging decomposition (256 threads): chunk8 = i*256 + t (i=0..1);
    // row = i*64 + (t>>2), slot = t&3 (4 slots of 8 elems per 32-elem row)
    const int tr = t >> 2, sl = t & 3;
    const int swsl = sl ^ (tr & 3);                         // row&3 == (t>>2)&3
    const float* gA0 = X + (size_t)(bm + tr) * K_DIM + sl * 8;          // linear f32 src
    const int wA0 = (tr * 4 + swsl) * 16;                                // swz LDS byte (A)
    const uint16_t* gB0 = Bw + (size_t)(bn + tr) * K_DIM + swsl * 8;     // pre-swz bf16 src
    const int ldsB0 = (t & ~63) * 16;                                    // wave-uniform (B)

    float4 ra[2][2];   // one K-tile of A per thread: i=0..1, float4 pair

    auto loadA_all = [&](int kt) {
        const int k0 = kt * BKt;
#pragma unroll
        for (int i = 0; i < 2; ++i) {
            const float* p = gA0 + (size_t)i * 64 * K_DIM + k0;
            ra[i][0] = *(const float4*)p;
            ra[i][1] = *(const float4*)(p + 4);
        }
    };
    auto stageB_all = [&](int d, int kt) {
        const int k0 = kt * BKt;
#pragma unroll
        for (int i = 0; i < 2; ++i)
            __builtin_amdgcn_global_load_lds(
                (const __attribute__((address_space(1))) void*)(gB0 + (size_t)i * 64 * K_DIM + k0),
                (__attribute__((address_space(3))) void*)((char*)&lds[d][1][0] + ldsB0 + i * 4096),
                16, 0, 0);
    };
    auto writeA_all = [&](int d) {
#pragma unroll
        for (int i = 0; i < 2; ++i) {
            union { u16x8 v; uint32_t u32[4]; } u;
            asm("v_cvt_pk_bf16_f32 %0, %1, %2" : "=v"(u.u32[0]) : "v"(ra[i][0].x), "v"(ra[i][0].y));
            asm("v_cvt_pk_bf16_f32 %0, %1, %2" : "=v"(u.u32[1]) : "v"(ra[i][0].z), "v"(ra[i][0].w));
            asm("v_cvt_pk_bf16_f32 %0, %1, %2" : "=v"(u.u32[2]) : "v"(ra[i][1].x), "v"(ra[i][1].y));
            asm("v_cvt_pk_bf16_f32 %0, %1, %2" : "=v"(u.u32[3]) : "v"(ra[i][1].z), "v"(ra[i][1].w));
            *(u16x8*)((char*)&lds[d][0][0] + wA0 + i * 4096) = u.v;
        }
    };
    // swizzled fragment read: element = row*32 + ((lhi ^ (row&3))*8); row&3 == lr&3
    auto loadFrag = [&](const uint16_t* base, int row) -> bf16x8 {
        return *(const bf16x8*)(base + row * 32 + ((lhi ^ xr3) * 8));
    };

    f32x4 acc[4][4] = {};

    // ---- prologue: buf0 staged (A(0) written, B(0) landed); A(1) in flight ----
    loadA_all(0);                            // 4 VMEM
    stageB_all(0, 0);                        // 2 VMEM
    __builtin_amdgcn_sched_barrier(0);
    writeA_all(0);                           // compiler inserts wait on A(0)
    __builtin_amdgcn_sched_barrier(0);
    loadA_all(1);                            // 4 VMEM
    __builtin_amdgcn_sched_barrier(0);
    asm volatile("s_waitcnt vmcnt(4)" ::: "memory");   // B(0) landed; A(1) in flight
    asm volatile("s_waitcnt lgkmcnt(0)" ::: "memory");
    __builtin_amdgcn_s_barrier();
    __builtin_amdgcn_sched_barrier(0);

    // ---- main loop: one barrier per K-tile ----
    for (int kt = 0; kt < NKT; ++kt) {
        const int cc = kt & 1;
        const uint16_t* bA = &lds[cc][0][0];
        const uint16_t* bB = &lds[cc][1][0];
        int ktn = kt + 1;  if (ktn >= NKT) ktn -= NKT;    // wrap: uniform counts
        int ktnn = kt + 2; if (ktnn >= NKT) ktnn -= NKT;

        // publish A(kt+1) -> buf[1-cc]; issue B(kt+1) (oldest), A(kt+2) (newest)
        writeA_all(1 - cc);
        __builtin_amdgcn_sched_barrier(0);
        stageB_all(1 - cc, ktn);
        loadA_all(ktnn);
        __builtin_amdgcn_sched_barrier(0);

        // compute on buf[cc]: 8 ds_read_b128 + 16 MFMA
        bf16x8 bfr[4], af[4];
#pragma unroll
        for (int n = 0; n < 4; ++n) bfr[n] = loadFrag(bB, wn + n * 16 + lr);
#pragma unroll
        for (int m = 0; m < 4; ++m) af[m] = loadFrag(bA, wm + m * 16 + lr);
        __builtin_amdgcn_s_setprio(1);
#pragma unroll
        for (int m = 0; m < 4; ++m)
#pragma unroll
            for (int n = 0; n < 4; ++n)
                acc[m][n] = __builtin_amdgcn_mfma_f32_16x16x32_bf16(af[m], bfr[n],
                                                                    acc[m][n], 0, 0, 0);
        __builtin_amdgcn_s_setprio(0);

        // boundary: B(kt+1) landed (6 outstanding -> 4); A(kt+2) stays in flight
        __builtin_amdgcn_sched_barrier(0);
        asm volatile("s_waitcnt vmcnt(4)" ::: "memory");
        asm volatile("s_waitcnt lgkmcnt(0)" ::: "memory");
        __builtin_amdgcn_s_barrier();
        __builtin_amdgcn_sched_barrier(0);
    }

    // ---- epilogue: C/D layout (m89): col = lane&15, row = (lane>>4)*4 + j ----
    const int cr = lhi * 4;
    const bool safe = ((long long)(bm + BMt) * NDIM) <= out_elems;
    if (safe) {
#pragma unroll
        for (int m = 0; m < 4; ++m) {
            int grow = bm + wm + m * 16 + cr;
#pragma unroll
            for (int j = 0; j < 4; ++j) {
                float* cp = C + (size_t)(grow + j) * NDIM + bn + wn + lr;
#pragma unroll
                for (int n = 0; n < 4; ++n)
                    cp[n * 16] = acc[m][n][j];
            }
        }
    } else {
        for (int m = 0; m < 4; ++m) {
            int grow = bm + wm + m * 16 + cr;
            for (int j = 0; j < 4; ++j) {
                long long base = (long long)(grow + j) * NDIM + bn + wn + lr;
                for (int n = 0; n < 4; ++n)
                    if (base + n * 16 < out_elems) C[base + n * 16] = acc[m][n][j];
            }
        }
    }
}

// ---- 128x128 gload_lds GEMM (fallback for the interleaved/2048 path) ----
template <int NDIM>
__global__ __launch_bounds__(256) void dft_gemm128(const uint16_t* __restrict__ A,
                                                   const uint16_t* __restrict__ B,
                                                   float* __restrict__ C,
                                                   long long out_elems) {
    constexpr int NT = NDIM / BN;
    __shared__ uint16_t As[BM * BK];
    __shared__ uint16_t Bs[BN * BK];

    const int t = threadIdx.x;
    const int l = t & 63;
    const int w = t >> 6;

    int bid = blockIdx.x;
    {
        int nwg = gridDim.x;
        if ((nwg & 7) == 0) { int q = nwg >> 3; bid = (bid & 7) * q + (bid >> 3); }
    }
    const int bm = (bid / NT) * BM;
    const int bn = (bid % NT) * BN;

    const uint16_t* gA[4];
    const uint16_t* gB[4];
    int ldsOff[4];
#pragma unroll
    for (int i = 0; i < 4; ++i) {
        int chunk = i * 256 + t;
        int row = chunk >> 3;
        int cc = (chunk & 7) * 8;
        gA[i] = A + (size_t)(bm + row) * K_DIM + cc;
        gB[i] = B + (size_t)(bn + row) * K_DIM + cc;
        ldsOff[i] = (i * 256 + (t & 192)) * 16;
    }

    const int wm = ((w >> 1) & 1) * 64;
    const int wn = (w & 1) * 64;
    const int lr = l & 15;
    const int lk = (l >> 4) * 8;

    f32x4 acc[4][4] = {};

    for (int k0 = 0; k0 < K_DIM; k0 += BK) {
#pragma unroll
        for (int i = 0; i < 4; ++i)
            __builtin_amdgcn_global_load_lds(
                (const __attribute__((address_space(1))) void*)(gA[i] + k0),
                (__attribute__((address_space(3))) void*)((char*)As + ldsOff[i]), 16, 0, 0);
#pragma unroll
        for (int i = 0; i < 4; ++i)
            __builtin_amdgcn_global_load_lds(
                (const __attribute__((address_space(1))) void*)(gB[i] + k0),
                (__attribute__((address_space(3))) void*)((char*)Bs + ldsOff[i]), 16, 0, 0);
        __syncthreads();
#pragma unroll
        for (int kk = 0; kk < BK; kk += 32) {
            bf16x8 af[4], bfr[4];
#pragma unroll
            for (int m = 0; m < 4; ++m)
                af[m] = *(const bf16x8*)&As[(wm + m * 16 + lr) * BK + kk + lk];
#pragma unroll
            for (int n = 0; n < 4; ++n)
                bfr[n] = *(const bf16x8*)&Bs[(wn + n * 16 + lr) * BK + kk + lk];
#pragma unroll
            for (int m = 0; m < 4; ++m)
#pragma unroll
                for (int n = 0; n < 4; ++n)
                    acc[m][n] = __builtin_amdgcn_mfma_f32_16x16x32_bf16(af[m], bfr[n],
                                                                        acc[m][n], 0, 0, 0);
        }
        __syncthreads();
    }

    const int cr = (l >> 4) * 4;
    const bool safe = ((long long)(bm + BM) * NDIM) <= out_elems;
    if (safe) {
#pragma unroll
        for (int m = 0; m < 4; ++m) {
            int grow = bm + wm + m * 16 + cr;
#pragma unroll
            for (int j = 0; j < 4; ++j) {
                float* cp = C + (size_t)(grow + j) * NDIM + bn + wn + lr;
#pragma unroll
                for (int n = 0; n < 4; ++n)
                    cp[n * 16] = acc[m][n][j];
            }
        }
    } else {
        for (int m = 0; m < 4; ++m) {
            int grow = bm + wm + m * 16 + cr;
            for (int j = 0; j < 4; ++j) {
                long long base = (long long)(grow + j) * NDIM + bn + wn + lr;
                for (int n = 0; n < 4; ++n)
                    if (base + n * 16 < out_elems) C[base + n * 16] = acc[m][n][j];
            }
        }
    }
}

// ---- fp32 fallback (only if ws too small) ----
__global__ void dft_naive(const float* __restrict__ x, const float* __restrict__ wsin,
                          const float* __restrict__ wcos, float* __restrict__ out,
                          long long out_elems, int real_only) {
    __shared__ float xs[K_DIM];
    int row = blockIdx.x;
    const float* xr = x + (size_t)row * K_DIM;
    for (int i = threadIdx.x; i < K_DIM; i += blockDim.x) xs[i] = xr[i];
    __syncthreads();
    for (int k = threadIdx.x; k < K_DIM; k += blockDim.x) {
        const float* wc = wcos + (size_t)k * K_DIM;
        float re = 0.f;
        if (real_only) {
            for (int s = 0; s < K_DIM; ++s) re += xs[s] * wc[s];
            long long o = (long long)row * K_DIM + k;
            if (o < out_elems) out[o] = re;
        } else {
            const float* ws = wsin + (size_t)k * K_DIM;
            float im = 0.f;
            for (int s = 0; s < K_DIM; ++s) { re += xs[s] * wc[s]; im += xs[s] * ws[s]; }
            long long o = ((long long)row * K_DIM + k) * 2;
            if (o + 1 < out_elems) { out[o] = re; out[o + 1] = -im; }
        }
    }
}

extern "C" void kernel_launch(void* const* d_in, const int* in_sizes, int n_in,
                              void* d_out, int out_size, void* d_ws, size_t ws_size,
                              hipStream_t stream) {
    const float* x    = (const float*)d_in[0];
    const float* wsin = (const float*)d_in[1];
    const float* wcos = (const float*)d_in[2];
    float* out = (float*)d_out;

    const int real_only = (out_size == M_TOT * 1024);
    const size_t need = (size_t)M_TOT * K_DIM * 2 + (size_t)2048 * K_DIM * 2;

    if (ws_size >= need) {
        uint16_t* xb = (uint16_t*)d_ws;
        uint16_t* Wb = xb + (size_t)M_TOT * K_DIM;
        if (real_only) {
            build_wc_kernel<<<512, 256, 0, stream>>>(wcos, Wb);
            dft_gemm128f<1024><<<(M_TOT / 128) * (1024 / 128), 256, 0, stream>>>(
                x, Wb, out, (long long)out_size);
        } else {
            cvt_x_kernel<<<2048, 256, 0, stream>>>(x, xb);
            build_w_kernel<<<512, 256, 0, stream>>>(wsin, wcos, Wb);
            dft_gemm128<2048><<<128 * 16, 256, 0, stream>>>(xb, Wb, out, (long long)out_size);
        }
    } else {
        dft_naive<<<M_TOT, 256, 0, stream>>>(x, wsin, wcos, out, (long long)out_size,
                                             real_only);
    }
}

// Round 11
// 57.098 us; speedup vs baseline: 1.0285x; 1.0285x over previous
//
#include <hip/hip_runtime.h>
#include <stdint.h>

#define K_DIM 1024
#define M_TOT 16384
#define BM 128
#define BN 128
#define BK 64

typedef __attribute__((ext_vector_type(8))) short bf16x8;
typedef __attribute__((ext_vector_type(4))) float f32x4;
typedef __attribute__((ext_vector_type(8))) unsigned short u16x8;

__device__ inline uint16_t f2bf(float f) {
    union { float f; uint32_t u; } v; v.f = f;
    return (uint16_t)((v.u + 0x7fffu + ((v.u >> 16) & 1u)) >> 16);
}

// ---- x (16M f32) -> bf16 (only used by the 2048 fallback path) ----
__global__ void cvt_x_kernel(const float* __restrict__ x, uint16_t* __restrict__ xb) {
    const size_t n8 = (size_t)M_TOT * K_DIM / 8;
    for (size_t i = (size_t)blockIdx.x * blockDim.x + threadIdx.x; i < n8;
         i += (size_t)gridDim.x * blockDim.x) {
        const float4* s = (const float4*)x + i * 2;
        float4 a = s[0], b = s[1];
        u16x8 v;
        v[0] = f2bf(a.x); v[1] = f2bf(a.y); v[2] = f2bf(a.z); v[3] = f2bf(a.w);
        v[4] = f2bf(b.x); v[5] = f2bf(b.y); v[6] = f2bf(b.z); v[7] = f2bf(b.w);
        *(u16x8*)(xb + i * 8) = v;
    }
}

// ---- real-only weights: Wc[k][s] = cos(2*pi*k*s/N), bf16 [1024][1024] ----
__global__ void build_wc_kernel(const float* __restrict__ wcos, uint16_t* __restrict__ W) {
    int i = blockIdx.x * blockDim.x + threadIdx.x;
    int k = i >> 7;
    int sc = (i & 127) * 8;
    const float4* c = (const float4*)(wcos + (size_t)k * K_DIM + sc);
    float4 c0 = c[0], c1 = c[1];
    u16x8 vc;
    vc[0] = f2bf(c0.x); vc[1] = f2bf(c0.y); vc[2] = f2bf(c0.z); vc[3] = f2bf(c0.w);
    vc[4] = f2bf(c1.x); vc[5] = f2bf(c1.y); vc[6] = f2bf(c1.z); vc[7] = f2bf(c1.w);
    *(u16x8*)(W + (size_t)k * K_DIM + sc) = vc;
}

// ---- interleaved weights (fallback path): W[2k][s]=cos, W[2k+1][s]=-sin ----
__global__ void build_w_kernel(const float* __restrict__ wsin, const float* __restrict__ wcos,
                               uint16_t* __restrict__ W) {
    int i = blockIdx.x * blockDim.x + threadIdx.x;
    int k = i >> 7;
    int sc = (i & 127) * 8;
    const float4* c = (const float4*)(wcos + (size_t)k * K_DIM + sc);
    const float4* s = (const float4*)(wsin + (size_t)k * K_DIM + sc);
    float4 c0 = c[0], c1 = c[1], s0 = s[0], s1 = s[1];
    u16x8 vc, vs;
    vc[0] = f2bf(c0.x); vc[1] = f2bf(c0.y); vc[2] = f2bf(c0.z); vc[3] = f2bf(c0.w);
    vc[4] = f2bf(c1.x); vc[5] = f2bf(c1.y); vc[6] = f2bf(c1.z); vc[7] = f2bf(c1.w);
    vs[0] = f2bf(-s0.x); vs[1] = f2bf(-s0.y); vs[2] = f2bf(-s0.z); vs[3] = f2bf(-s0.w);
    vs[4] = f2bf(-s1.x); vs[5] = f2bf(-s1.y); vs[6] = f2bf(-s1.z); vs[7] = f2bf(-s1.w);
    *(u16x8*)(W + (size_t)(2 * k) * K_DIM + sc) = vc;
    *(u16x8*)(W + (size_t)(2 * k + 1) * K_DIM + sc) = vs;
}

// =====================================================================
// Fused-cvt 128x128 / BK=64 bf16 MFMA GEMM — DUAL-BLOCK variant:
//   Same machinery as the proven 256x256/1-barrier kernel (slot^(row&7)
//   swizzle on 128-B rows = 0 conflicts; counted vmcnt(8); fused A path),
//   but LDS = 64 KiB -> 2 independent blocks/CU: the co-resident block
//   fills barrier/VMEM stalls and overlaps the C-write tail (m114).
//   Per-thread staging counts identical to the 256^2 version (8 A-f32
//   loads + 4 B gload_lds) so all wait literals carry over.
// =====================================================================
template <int NDIM>
__global__ __launch_bounds__(256, 2) void dft_gemm128d(const float* __restrict__ X,
                                                       const uint16_t* __restrict__ Bw,
                                                       float* __restrict__ C,
                                                       long long out_elems) {
    constexpr int BMt = 128, BKt = 64;
    constexpr int NT = NDIM / 128;        // n-tiles (8)
    constexpr int NKT = K_DIM / BKt;      // 16 K-tiles
    __shared__ uint16_t lds[2][2][BMt * BKt];   // [dbuf][A=0/B=1][128*64] = 64 KiB

    const int t = threadIdx.x;
    const int l = t & 63;
    const int w = t >> 6;                 // 0..3
    const int wm = (w >> 1) * 64;
    const int wn = (w & 1) * 64;
    const int lr = l & 15;
    const int lhi = l >> 4;               // 0..3
    const int xr7 = lr & 7;

    // T1: bijective XCD swizzle (nwg = 1024, %8==0). q=128 -> the 8 bn-blocks
    // sharing an A panel are consecutive within one XCD (A panel L2-resident).
    int bid = blockIdx.x;
    {
        int nwg = gridDim.x;
        if ((nwg & 7) == 0) { int q = nwg >> 3; bid = (bid & 7) * q + (bid >> 3); }
    }
    const int bm = (bid / NT) * BMt;
    const int bn = (bid % NT) * 128;

    // staging: 1024 chunks of 16 B = [128 rows][8 slots]; thread t handles
    // rows r0 + i*32 (i=0..3), slot sl; row&7 == r0&7 (i*32 ≡ 0 mod 8).
    const int r0 = t >> 3, sl = t & 7;
    const int swsl = sl ^ (r0 & 7);
    const float* gA0 = X + (size_t)(bm + r0) * K_DIM + sl * 8;          // linear f32 src
    const int wA0 = (r0 * 8 + swsl) * 16;                                // swz LDS byte (A)
    const uint16_t* gB0 = Bw + (size_t)(bn + r0) * K_DIM + swsl * 8;     // pre-swz bf16 src
    const int ldsB0 = (t & ~63) * 16;                                    // wave-uniform (B)

    float4 ra[4][2];   // one K-tile of A per thread (8 float4 in flight)

    auto loadA_all = [&](int kt) {
        const int k0 = kt * BKt;
#pragma unroll
        for (int i = 0; i < 4; ++i) {
            const float* p = gA0 + (size_t)i * 32 * K_DIM + k0;
            ra[i][0] = *(const float4*)p;
            ra[i][1] = *(const float4*)(p + 4);
        }
    };
    auto stageB_all = [&](int d, int kt) {
        const int k0 = kt * BKt;
#pragma unroll
        for (int i = 0; i < 4; ++i)
            __builtin_amdgcn_global_load_lds(
                (const __attribute__((address_space(1))) void*)(gB0 + (size_t)i * 32 * K_DIM + k0),
                (__attribute__((address_space(3))) void*)((char*)&lds[d][1][0] + ldsB0 + i * 4096),
                16, 0, 0);
    };
    auto writeA_all = [&](int d) {
#pragma unroll
        for (int i = 0; i < 4; ++i) {
            union { u16x8 v; uint32_t u32[4]; } u;
            asm("v_cvt_pk_bf16_f32 %0, %1, %2" : "=v"(u.u32[0]) : "v"(ra[i][0].x), "v"(ra[i][0].y));
            asm("v_cvt_pk_bf16_f32 %0, %1, %2" : "=v"(u.u32[1]) : "v"(ra[i][0].z), "v"(ra[i][0].w));
            asm("v_cvt_pk_bf16_f32 %0, %1, %2" : "=v"(u.u32[2]) : "v"(ra[i][1].x), "v"(ra[i][1].y));
            asm("v_cvt_pk_bf16_f32 %0, %1, %2" : "=v"(u.u32[3]) : "v"(ra[i][1].z), "v"(ra[i][1].w));
            *(u16x8*)((char*)&lds[d][0][0] + wA0 + i * 4096) = u.v;
        }
    };
    // swizzled fragment read: element = row*64 + ((slot ^ (row&7))*8)
    auto loadFrag = [&](const uint16_t* base, int row, int kk) -> bf16x8 {
        int s = (kk >> 3) + lhi;
        return *(const bf16x8*)(base + row * 64 + ((s ^ xr7) * 8));
    };

    f32x4 acc[4][4] = {};

    // ---- prologue: buf0 staged (A(0) written, B(0) landed); A(1) in flight ----
    loadA_all(0);                            // 8 VMEM
    stageB_all(0, 0);                        // 4 VMEM
    __builtin_amdgcn_sched_barrier(0);
    writeA_all(0);                           // compiler inserts wait on A(0)
    __builtin_amdgcn_sched_barrier(0);
    loadA_all(1);                            // 8 VMEM
    __builtin_amdgcn_sched_barrier(0);
    asm volatile("s_waitcnt vmcnt(8)" ::: "memory");   // B(0) landed; A(1) in flight
    asm volatile("s_waitcnt lgkmcnt(0)" ::: "memory");
    __builtin_amdgcn_s_barrier();
    __builtin_amdgcn_sched_barrier(0);

    // ---- main loop: one barrier per K-tile ----
    for (int kt = 0; kt < NKT; ++kt) {
        const int cc = kt & 1;
        const uint16_t* bA = &lds[cc][0][0];
        const uint16_t* bB = &lds[cc][1][0];
        int ktn = kt + 1;  if (ktn >= NKT) ktn -= NKT;    // wrap: uniform counts
        int ktnn = kt + 2; if (ktnn >= NKT) ktnn -= NKT;

        // publish A(kt+1) -> buf[1-cc]; issue B(kt+1) (oldest), A(kt+2) (newest)
        writeA_all(1 - cc);
        __builtin_amdgcn_sched_barrier(0);
        stageB_all(1 - cc, ktn);
        loadA_all(ktnn);
        __builtin_amdgcn_sched_barrier(0);

        // compute on buf[cc]: 16 ds_read_b128 + 32 MFMA (no intra-tile barriers)
#pragma unroll
        for (int ks = 0; ks < 2; ++ks) {
            const int kk = ks * 32;
            bf16x8 bfr[4], af[4];
#pragma unroll
            for (int n = 0; n < 4; ++n) bfr[n] = loadFrag(bB, wn + n * 16 + lr, kk);
#pragma unroll
            for (int m = 0; m < 4; ++m) af[m] = loadFrag(bA, wm + m * 16 + lr, kk);
#pragma unroll
            for (int m = 0; m < 4; ++m)
#pragma unroll
                for (int n = 0; n < 4; ++n)
                    acc[m][n] = __builtin_amdgcn_mfma_f32_16x16x32_bf16(af[m], bfr[n],
                                                                        acc[m][n], 0, 0, 0);
        }

        // boundary: B(kt+1) landed (12 outstanding -> 8); A(kt+2) stays in flight
        __builtin_amdgcn_sched_barrier(0);
        asm volatile("s_waitcnt vmcnt(8)" ::: "memory");
        asm volatile("s_waitcnt lgkmcnt(0)" ::: "memory");
        __builtin_amdgcn_s_barrier();
        __builtin_amdgcn_sched_barrier(0);
    }

    // ---- epilogue: C/D layout (m89): col = lane&15, row = (lane>>4)*4 + j ----
    const int cr = lhi * 4;
    const bool safe = ((long long)(bm + BMt) * NDIM) <= out_elems;
    if (safe) {
#pragma unroll
        for (int m = 0; m < 4; ++m) {
            int grow = bm + wm + m * 16 + cr;
#pragma unroll
            for (int j = 0; j < 4; ++j) {
                float* cp = C + (size_t)(grow + j) * NDIM + bn + wn + lr;
#pragma unroll
                for (int n = 0; n < 4; ++n)
                    cp[n * 16] = acc[m][n][j];
            }
        }
    } else {
        for (int m = 0; m < 4; ++m) {
            int grow = bm + wm + m * 16 + cr;
            for (int j = 0; j < 4; ++j) {
                long long base = (long long)(grow + j) * NDIM + bn + wn + lr;
                for (int n = 0; n < 4; ++n)
                    if (base + n * 16 < out_elems) C[base + n * 16] = acc[m][n][j];
            }
        }
    }
}

// ---- 128x128 gload_lds GEMM (fallback for the interleaved/2048 path) ----
template <int NDIM>
__global__ __launch_bounds__(256) void dft_gemm128(const uint16_t* __restrict__ A,
                                                   const uint16_t* __restrict__ B,
                                                   float* __restrict__ C,
                                                   long long out_elems) {
    constexpr int NT = NDIM / BN;
    __shared__ uint16_t As[BM * BK];
    __shared__ uint16_t Bs[BN * BK];

    const int t = threadIdx.x;
    const int l = t & 63;
    const int w = t >> 6;

    int bid = blockIdx.x;
    {
        int nwg = gridDim.x;
        if ((nwg & 7) == 0) { int q = nwg >> 3; bid = (bid & 7) * q + (bid >> 3); }
    }
    const int bm = (bid / NT) * BM;
    const int bn = (bid % NT) * BN;

    const uint16_t* gA[4];
    const uint16_t* gB[4];
    int ldsOff[4];
#pragma unroll
    for (int i = 0; i < 4; ++i) {
        int chunk = i * 256 + t;
        int row = chunk >> 3;
        int cc = (chunk & 7) * 8;
        gA[i] = A + (size_t)(bm + row) * K_DIM + cc;
        gB[i] = B + (size_t)(bn + row) * K_DIM + cc;
        ldsOff[i] = (i * 256 + (t & 192)) * 16;
    }

    const int wm = ((w >> 1) & 1) * 64;
    const int wn = (w & 1) * 64;
    const int lr = l & 15;
    const int lk = (l >> 4) * 8;

    f32x4 acc[4][4] = {};

    for (int k0 = 0; k0 < K_DIM; k0 += BK) {
#pragma unroll
        for (int i = 0; i < 4; ++i)
            __builtin_amdgcn_global_load_lds(
                (const __attribute__((address_space(1))) void*)(gA[i] + k0),
                (__attribute__((address_space(3))) void*)((char*)As + ldsOff[i]), 16, 0, 0);
#pragma unroll
        for (int i = 0; i < 4; ++i)
            __builtin_amdgcn_global_load_lds(
                (const __attribute__((address_space(1))) void*)(gB[i] + k0),
                (__attribute__((address_space(3))) void*)((char*)Bs + ldsOff[i]), 16, 0, 0);
        __syncthreads();
#pragma unroll
        for (int kk = 0; kk < BK; kk += 32) {
            bf16x8 af[4], bfr[4];
#pragma unroll
            for (int m = 0; m < 4; ++m)
                af[m] = *(const bf16x8*)&As[(wm + m * 16 + lr) * BK + kk + lk];
#pragma unroll
            for (int n = 0; n < 4; ++n)
                bfr[n] = *(const bf16x8*)&Bs[(wn + n * 16 + lr) * BK + kk + lk];
#pragma unroll
            for (int m = 0; m < 4; ++m)
#pragma unroll
                for (int n = 0; n < 4; ++n)
                    acc[m][n] = __builtin_amdgcn_mfma_f32_16x16x32_bf16(af[m], bfr[n],
                                                                        acc[m][n], 0, 0, 0);
        }
        __syncthreads();
    }

    const int cr = (l >> 4) * 4;
    const bool safe = ((long long)(bm + BM) * NDIM) <= out_elems;
    if (safe) {
#pragma unroll
        for (int m = 0; m < 4; ++m) {
            int grow = bm + wm + m * 16 + cr;
#pragma unroll
            for (int j = 0; j < 4; ++j) {
                float* cp = C + (size_t)(grow + j) * NDIM + bn + wn + lr;
#pragma unroll
                for (int n = 0; n < 4; ++n)
                    cp[n * 16] = acc[m][n][j];
            }
        }
    } else {
        for (int m = 0; m < 4; ++m) {
            int grow = bm + wm + m * 16 + cr;
            for (int j = 0; j < 4; ++j) {
                long long base = (long long)(grow + j) * NDIM + bn + wn + lr;
                for (int n = 0; n < 4; ++n)
                    if (base + n * 16 < out_elems) C[base + n * 16] = acc[m][n][j];
            }
        }
    }
}

// ---- fp32 fallback (only if ws too small) ----
__global__ void dft_naive(const float* __restrict__ x, const float* __restrict__ wsin,
                          const float* __restrict__ wcos, float* __restrict__ out,
                          long long out_elems, int real_only) {
    __shared__ float xs[K_DIM];
    int row = blockIdx.x;
    const float* xr = x + (size_t)row * K_DIM;
    for (int i = threadIdx.x; i < K_DIM; i += blockDim.x) xs[i] = xr[i];
    __syncthreads();
    for (int k = threadIdx.x; k < K_DIM; k += blockDim.x) {
        const float* wc = wcos + (size_t)k * K_DIM;
        float re = 0.f;
        if (real_only) {
            for (int s = 0; s < K_DIM; ++s) re += xs[s] * wc[s];
            long long o = (long long)row * K_DIM + k;
            if (o < out_elems) out[o] = re;
        } else {
            const float* ws = wsin + (size_t)k * K_DIM;
            float im = 0.f;
            for (int s = 0; s < K_DIM; ++s) { re += xs[s] * wc[s]; im += xs[s] * ws[s]; }
            long long o = ((long long)row * K_DIM + k) * 2;
            if (o + 1 < out_elems) { out[o] = re; out[o + 1] = -im; }
        }
    }
}

extern "C" void kernel_launch(void* const* d_in, const int* in_sizes, int n_in,
                              void* d_out, int out_size, void* d_ws, size_t ws_size,
                              hipStream_t stream) {
    const float* x    = (const float*)d_in[0];
    const float* wsin = (const float*)d_in[1];
    const float* wcos = (const float*)d_in[2];
    float* out = (float*)d_out;

    const int real_only = (out_size == M_TOT * 1024);
    const size_t need = (size_t)M_TOT * K_DIM * 2 + (size_t)2048 * K_DIM * 2;

    if (ws_size >= need) {
        uint16_t* xb = (uint16_t*)d_ws;
        uint16_t* Wb = xb + (size_t)M_TOT * K_DIM;
        if (real_only) {
            build_wc_kernel<<<512, 256, 0, stream>>>(wcos, Wb);
            dft_gemm128d<1024><<<(M_TOT / 128) * (1024 / 128), 256, 0, stream>>>(
                x, Wb, out, (long long)out_size);
        } else {
            cvt_x_kernel<<<2048, 256, 0, stream>>>(x, xb);
            build_w_kernel<<<512, 256, 0, stream>>>(wsin, wcos, Wb);
            dft_gemm128<2048><<<128 * 16, 256, 0, stream>>>(xb, Wb, out, (long long)out_size);
        }
    } else {
        dft_naive<<<M_TOT, 256, 0, stream>>>(x, wsin, wcos, out, (long long)out_size,
                                             real_only);
    }
}

// Round 12
// 40.403 us; speedup vs baseline: 1.4535x; 1.4132x over previous
//
#include <hip/hip_runtime.h>
#include <stdint.h>

#define K_DIM 1024
#define M_TOT 16384
#define BM 128
#define BN 128
#define BK 64

typedef __attribute__((ext_vector_type(8))) short bf16x8;
typedef __attribute__((ext_vector_type(4))) float f32x4;
typedef __attribute__((ext_vector_type(8))) unsigned short u16x8;

__device__ inline uint16_t f2bf(float f) {
    union { float f; uint32_t u; } v; v.f = f;
    return (uint16_t)((v.u + 0x7fffu + ((v.u >> 16) & 1u)) >> 16);
}

// ---- x (16M f32) -> bf16 (only used by the 2048 fallback path) ----
__global__ void cvt_x_kernel(const float* __restrict__ x, uint16_t* __restrict__ xb) {
    const size_t n8 = (size_t)M_TOT * K_DIM / 8;
    for (size_t i = (size_t)blockIdx.x * blockDim.x + threadIdx.x; i < n8;
         i += (size_t)gridDim.x * blockDim.x) {
        const float4* s = (const float4*)x + i * 2;
        float4 a = s[0], b = s[1];
        u16x8 v;
        v[0] = f2bf(a.x); v[1] = f2bf(a.y); v[2] = f2bf(a.z); v[3] = f2bf(a.w);
        v[4] = f2bf(b.x); v[5] = f2bf(b.y); v[6] = f2bf(b.z); v[7] = f2bf(b.w);
        *(u16x8*)(xb + i * 8) = v;
    }
}

// ---- real weights rows k=0..511 only (k>=512 handled by symmetry) ----
__global__ void build_wc_kernel(const float* __restrict__ wcos, uint16_t* __restrict__ W) {
    int i = blockIdx.x * blockDim.x + threadIdx.x;   // 65536 threads -> k in [0,512)
    int k = i >> 7;
    int sc = (i & 127) * 8;
    const float4* c = (const float4*)(wcos + (size_t)k * K_DIM + sc);
    float4 c0 = c[0], c1 = c[1];
    u16x8 vc;
    vc[0] = f2bf(c0.x); vc[1] = f2bf(c0.y); vc[2] = f2bf(c0.z); vc[3] = f2bf(c0.w);
    vc[4] = f2bf(c1.x); vc[5] = f2bf(c1.y); vc[6] = f2bf(c1.z); vc[7] = f2bf(c1.w);
    *(u16x8*)(W + (size_t)k * K_DIM + sc) = vc;
}

// ---- interleaved weights (fallback path): W[2k][s]=cos, W[2k+1][s]=-sin ----
__global__ void build_w_kernel(const float* __restrict__ wsin, const float* __restrict__ wcos,
                               uint16_t* __restrict__ W) {
    int i = blockIdx.x * blockDim.x + threadIdx.x;
    int k = i >> 7;
    int sc = (i & 127) * 8;
    const float4* c = (const float4*)(wcos + (size_t)k * K_DIM + sc);
    const float4* s = (const float4*)(wsin + (size_t)k * K_DIM + sc);
    float4 c0 = c[0], c1 = c[1], s0 = s[0], s1 = s[1];
    u16x8 vc, vs;
    vc[0] = f2bf(c0.x); vc[1] = f2bf(c0.y); vc[2] = f2bf(c0.z); vc[3] = f2bf(c0.w);
    vc[4] = f2bf(c1.x); vc[5] = f2bf(c1.y); vc[6] = f2bf(c1.z); vc[7] = f2bf(c1.w);
    vs[0] = f2bf(-s0.x); vs[1] = f2bf(-s0.y); vs[2] = f2bf(-s0.z); vs[3] = f2bf(-s0.w);
    vs[4] = f2bf(-s1.x); vs[5] = f2bf(-s1.y); vs[6] = f2bf(-s1.z); vs[7] = f2bf(-s1.w);
    *(u16x8*)(W + (size_t)(2 * k) * K_DIM + sc) = vc;
    *(u16x8*)(W + (size_t)(2 * k + 1) * K_DIM + sc) = vs;
}

// =====================================================================
// SYMMETRY-HALVED fused-cvt bf16 MFMA GEMM.
//   out[m][k] = sum_s x[m][s] cos(2*pi*k*s/1024);  cos even in k =>
//   out[:,1024-k] == out[:,k].  Compute k=0..511 only (half the FLOPs),
//   write straight + mirrored columns; k=512 (Nyquist) = sum x*(-1)^s,
//   accumulated for free from the f32 A data during staging.
//   Tile 128x256, BK=64, 512 thr / 8 waves (wr 0..1 x wc 0..3), grid
//   256 = 1 block/CU; bm=bid>>1,bn=bid&1 so A-panel pairs share an XCD.
//   Machinery proven in earlier rounds: fused A (reg f32 -> cvt_pk ->
//   swizzled ds_write), B via global_load_lds w/ pre-swizzled source,
//   slot^(row&7) both-sides swizzle (0 conflicts), 1 barrier per K-tile,
//   counted vmcnt(4) (A loads never drained in-loop).
// =====================================================================
__global__ __launch_bounds__(512) void dft_gemm_half(const float* __restrict__ X,
                                                     const uint16_t* __restrict__ Bw,
                                                     float* __restrict__ C) {
    constexpr int NKT = K_DIM / 64;           // 16 K-tiles
    __shared__ uint16_t lds[2][24576];        // per buf: A[128*64] @0, B[256*64] @elem 8192

    const int t = threadIdx.x;
    const int l = t & 63;
    const int wid = t >> 6;
    const int wr = wid >> 2;      // 0..1  (64-row half)
    const int wc = wid & 3;       // 0..3  (64-col quarter)
    const int lr = l & 15;
    const int lhi = l >> 4;
    const int xr7 = lr & 7;

    // T1: bijective XCD swizzle (nwg = 256, %8==0)
    int bid = blockIdx.x;
    {
        int nwg = gridDim.x;
        if ((nwg & 7) == 0) { int q = nwg >> 3; bid = (bid & 7) * q + (bid >> 3); }
    }
    const int bm = (bid >> 1) * 128;      // pairs (2m,2m+1) share A-panel, same XCD
    const int bn256 = (bid & 1) * 256;    // k-columns [bn256, bn256+256)

    // staging: rows r0 + i*64, slot sl (8 elems = 16 B); row&7 == r0&7
    const int r0 = t >> 3, sl = t & 7;
    const int swsl = sl ^ (r0 & 7);
    const float* gA0 = X + (size_t)(bm + r0) * K_DIM + sl * 8;            // linear f32 src
    const int wA0 = (r0 * 8 + swsl) * 16;                                  // swz LDS byte (A)
    const uint16_t* gB0 = Bw + (size_t)(bn256 + r0) * K_DIM + swsl * 8;    // pre-swz src
    const int ldsB0 = 16384 + (t & ~63) * 16;                              // B byte base

    float4 ra[2][2];        // one K-tile of A per thread (rows r0, r0+64)
    float nyq[2] = {0.f, 0.f};

    auto loadA_all = [&](int kt) {
        const int k0 = kt * 64;
#pragma unroll
        for (int i = 0; i < 2; ++i) {
            const float* p = gA0 + (size_t)i * 64 * K_DIM + k0;
            ra[i][0] = *(const float4*)p;
            ra[i][1] = *(const float4*)(p + 4);
        }
    };
    auto stageB_all = [&](int d, int kt) {
        const int k0 = kt * 64;
#pragma unroll
        for (int i = 0; i < 4; ++i)
            __builtin_amdgcn_global_load_lds(
                (const __attribute__((address_space(1))) void*)(gB0 + (size_t)i * 64 * K_DIM + k0),
                (__attribute__((address_space(3))) void*)((char*)&lds[d][0] + ldsB0 + i * 8192),
                16, 0, 0);
    };
    auto writeA_all = [&](int d, bool donyq) {
#pragma unroll
        for (int i = 0; i < 2; ++i) {
            union { u16x8 v; uint32_t u32[4]; } u;
            asm("v_cvt_pk_bf16_f32 %0, %1, %2" : "=v"(u.u32[0]) : "v"(ra[i][0].x), "v"(ra[i][0].y));
            asm("v_cvt_pk_bf16_f32 %0, %1, %2" : "=v"(u.u32[1]) : "v"(ra[i][0].z), "v"(ra[i][0].w));
            asm("v_cvt_pk_bf16_f32 %0, %1, %2" : "=v"(u.u32[2]) : "v"(ra[i][1].x), "v"(ra[i][1].y));
            asm("v_cvt_pk_bf16_f32 %0, %1, %2" : "=v"(u.u32[3]) : "v"(ra[i][1].z), "v"(ra[i][1].w));
            *(u16x8*)((char*)&lds[d][0] + wA0 + i * 8192) = u.v;
            if (donyq)   // col = kt*64 + sl*8 + j -> parity = j&1
                nyq[i] += (ra[i][0].x - ra[i][0].y) + (ra[i][0].z - ra[i][0].w)
                        + (ra[i][1].x - ra[i][1].y) + (ra[i][1].z - ra[i][1].w);
        }
    };
    // swizzled fragment read: element = row*64 + ((slot ^ (row&7))*8)
    auto loadFragA = [&](const uint16_t* buf, int row, int kk) -> bf16x8 {
        int s = (kk >> 3) + lhi;
        return *(const bf16x8*)(buf + row * 64 + ((s ^ xr7) * 8));
    };

    f32x4 acc[4][4] = {};

    // ---- prologue ----
    loadA_all(0);                            // 4 VMEM (oldest)
    stageB_all(0, 0);                        // 4 VMEM
    __builtin_amdgcn_sched_barrier(0);
    asm volatile("s_waitcnt vmcnt(4)" ::: "memory");   // A(0) landed; B(0) in flight
    __builtin_amdgcn_sched_barrier(0);
    writeA_all(0, true);                     // publish A(0); nyq tile 0
    loadA_all(1);                            // 4 VMEM
    __builtin_amdgcn_sched_barrier(0);
    asm volatile("s_waitcnt vmcnt(4)" ::: "memory");   // B(0) landed; A(1) in flight
    asm volatile("s_waitcnt lgkmcnt(0)" ::: "memory");
    __builtin_amdgcn_s_barrier();
    __builtin_amdgcn_sched_barrier(0);

    // ---- main loop: one barrier per K-tile ----
    for (int kt = 0; kt < NKT; ++kt) {
        const int cc = kt & 1;
        const uint16_t* bA = &lds[cc][0];
        const uint16_t* bB = &lds[cc][8192];
        int ktn = kt + 1;  if (ktn >= NKT) ktn -= NKT;    // wrap: uniform counts
        int ktnn = kt + 2; if (ktnn >= NKT) ktnn -= NKT;

        // publish A(kt+1) -> buf[1-cc] (nyq-guard against the wrap); issue
        // B(kt+1) (oldest), A(kt+2) (newest)
        writeA_all(1 - cc, kt + 1 < NKT);
        __builtin_amdgcn_sched_barrier(0);
        stageB_all(1 - cc, ktn);
        loadA_all(ktnn);
        __builtin_amdgcn_sched_barrier(0);

        // compute on buf[cc]: 16 ds_read_b128 + 32 MFMA, no intra-tile barriers
#pragma unroll
        for (int ks = 0; ks < 2; ++ks) {
            const int kk = ks * 32;
            bf16x8 bfr[4], af[4];
#pragma unroll
            for (int n = 0; n < 4; ++n) bfr[n] = loadFragA(bB, wc * 64 + n * 16 + lr, kk);
#pragma unroll
            for (int m = 0; m < 4; ++m) af[m] = loadFragA(bA, wr * 64 + m * 16 + lr, kk);
            __builtin_amdgcn_s_setprio(1);
#pragma unroll
            for (int m = 0; m < 4; ++m)
#pragma unroll
                for (int n = 0; n < 4; ++n)
                    acc[m][n] = __builtin_amdgcn_mfma_f32_16x16x32_bf16(af[m], bfr[n],
                                                                        acc[m][n], 0, 0, 0);
            __builtin_amdgcn_s_setprio(0);
        }

        // boundary: B(kt+1) landed (8 outstanding -> 4); A(kt+2) stays in flight
        __builtin_amdgcn_sched_barrier(0);
        asm volatile("s_waitcnt vmcnt(4)" ::: "memory");
        asm volatile("s_waitcnt lgkmcnt(0)" ::: "memory");
        __builtin_amdgcn_s_barrier();
        __builtin_amdgcn_sched_barrier(0);
    }

    // ---- Nyquist column k=512 (bn==0 blocks): reduce per-thread partials ----
    if (bn256 == 0) {
        float* nl = (float*)&lds[0][0];      // 128 rows x 8 slots f32 (4 KB)
        nl[r0 * 8 + sl] = nyq[0];
        nl[(64 + r0) * 8 + sl] = nyq[1];
        __syncthreads();
        if (t < 128) {
            float s = 0.f;
#pragma unroll
            for (int j = 0; j < 8; ++j) s += nl[t * 8 + j];
            C[(size_t)(bm + t) * 1024 + 512] = s;
        }
    }

    // ---- epilogue: straight k + mirrored 1024-k.  C/D layout (m89):
    //      col = lane&15, row = (lane>>4)*4 + j ----
    const int cr = lhi * 4;
#pragma unroll
    for (int m = 0; m < 4; ++m) {
        int grow = bm + wr * 64 + m * 16 + cr;
#pragma unroll
        for (int j = 0; j < 4; ++j) {
            size_t base = (size_t)(grow + j) * 1024;
#pragma unroll
            for (int n = 0; n < 4; ++n) {
                int col = bn256 + wc * 64 + n * 16 + lr;
                float v = acc[m][n][j];
                C[base + col] = v;
                if (col) C[base + 1024 - col] = v;   // k=0 has no mirror
            }
        }
    }
}

// ---- 128x128 gload_lds GEMM (fallback for the interleaved/2048 path) ----
template <int NDIM>
__global__ __launch_bounds__(256) void dft_gemm128(const uint16_t* __restrict__ A,
                                                   const uint16_t* __restrict__ B,
                                                   float* __restrict__ C,
                                                   long long out_elems) {
    constexpr int NT = NDIM / BN;
    __shared__ uint16_t As[BM * BK];
    __shared__ uint16_t Bs[BN * BK];

    const int t = threadIdx.x;
    const int l = t & 63;
    const int w = t >> 6;

    int bid = blockIdx.x;
    {
        int nwg = gridDim.x;
        if ((nwg & 7) == 0) { int q = nwg >> 3; bid = (bid & 7) * q + (bid >> 3); }
    }
    const int bm = (bid / NT) * BM;
    const int bn = (bid % NT) * BN;

    const uint16_t* gA[4];
    const uint16_t* gB[4];
    int ldsOff[4];
#pragma unroll
    for (int i = 0; i < 4; ++i) {
        int chunk = i * 256 + t;
        int row = chunk >> 3;
        int cc = (chunk & 7) * 8;
        gA[i] = A + (size_t)(bm + row) * K_DIM + cc;
        gB[i] = B + (size_t)(bn + row) * K_DIM + cc;
        ldsOff[i] = (i * 256 + (t & 192)) * 16;
    }

    const int wm = ((w >> 1) & 1) * 64;
    const int wn = (w & 1) * 64;
    const int lr = l & 15;
    const int lk = (l >> 4) * 8;

    f32x4 acc[4][4] = {};

    for (int k0 = 0; k0 < K_DIM; k0 += BK) {
#pragma unroll
        for (int i = 0; i < 4; ++i)
            __builtin_amdgcn_global_load_lds(
                (const __attribute__((address_space(1))) void*)(gA[i] + k0),
                (__attribute__((address_space(3))) void*)((char*)As + ldsOff[i]), 16, 0, 0);
#pragma unroll
        for (int i = 0; i < 4; ++i)
            __builtin_amdgcn_global_load_lds(
                (const __attribute__((address_space(1))) void*)(gB[i] + k0),
                (__attribute__((address_space(3))) void*)((char*)Bs + ldsOff[i]), 16, 0, 0);
        __syncthreads();
#pragma unroll
        for (int kk = 0; kk < BK; kk += 32) {
            bf16x8 af[4], bfr[4];
#pragma unroll
            for (int m = 0; m < 4; ++m)
                af[m] = *(const bf16x8*)&As[(wm + m * 16 + lr) * BK + kk + lk];
#pragma unroll
            for (int n = 0; n < 4; ++n)
                bfr[n] = *(const bf16x8*)&Bs[(wn + n * 16 + lr) * BK + kk + lk];
#pragma unroll
            for (int m = 0; m < 4; ++m)
#pragma unroll
                for (int n = 0; n < 4; ++n)
                    acc[m][n] = __builtin_amdgcn_mfma_f32_16x16x32_bf16(af[m], bfr[n],
                                                                        acc[m][n], 0, 0, 0);
        }
        __syncthreads();
    }

    const int cr = (l >> 4) * 4;
    const bool safe = ((long long)(bm + BM) * NDIM) <= out_elems;
    if (safe) {
#pragma unroll
        for (int m = 0; m < 4; ++m) {
            int grow = bm + wm + m * 16 + cr;
#pragma unroll
            for (int j = 0; j < 4; ++j) {
                float* cp = C + (size_t)(grow + j) * NDIM + bn + wn + lr;
#pragma unroll
                for (int n = 0; n < 4; ++n)
                    cp[n * 16] = acc[m][n][j];
            }
        }
    } else {
        for (int m = 0; m < 4; ++m) {
            int grow = bm + wm + m * 16 + cr;
            for (int j = 0; j < 4; ++j) {
                long long base = (long long)(grow + j) * NDIM + bn + wn + lr;
                for (int n = 0; n < 4; ++n)
                    if (base + n * 16 < out_elems) C[base + n * 16] = acc[m][n][j];
            }
        }
    }
}

// ---- fp32 fallback (only if ws too small) ----
__global__ void dft_naive(const float* __restrict__ x, const float* __restrict__ wsin,
                          const float* __restrict__ wcos, float* __restrict__ out,
                          long long out_elems, int real_only) {
    __shared__ float xs[K_DIM];
    int row = blockIdx.x;
    const float* xr = x + (size_t)row * K_DIM;
    for (int i = threadIdx.x; i < K_DIM; i += blockDim.x) xs[i] = xr[i];
    __syncthreads();
    for (int k = threadIdx.x; k < K_DIM; k += blockDim.x) {
        const float* wc = wcos + (size_t)k * K_DIM;
        float re = 0.f;
        if (real_only) {
            for (int s = 0; s < K_DIM; ++s) re += xs[s] * wc[s];
            long long o = (long long)row * K_DIM + k;
            if (o < out_elems) out[o] = re;
        } else {
            const float* ws = wsin + (size_t)k * K_DIM;
            float im = 0.f;
            for (int s = 0; s < K_DIM; ++s) { re += xs[s] * wc[s]; im += xs[s] * ws[s]; }
            long long o = ((long long)row * K_DIM + k) * 2;
            if (o + 1 < out_elems) { out[o] = re; out[o + 1] = -im; }
        }
    }
}

extern "C" void kernel_launch(void* const* d_in, const int* in_sizes, int n_in,
                              void* d_out, int out_size, void* d_ws, size_t ws_size,
                              hipStream_t stream) {
    const float* x    = (const float*)d_in[0];
    const float* wsin = (const float*)d_in[1];
    const float* wcos = (const float*)d_in[2];
    float* out = (float*)d_out;

    const int real_only = (out_size == M_TOT * 1024);
    const size_t need = (size_t)M_TOT * K_DIM * 2 + (size_t)2048 * K_DIM * 2;

    if (ws_size >= need) {
        uint16_t* xb = (uint16_t*)d_ws;
        uint16_t* Wb = xb + (size_t)M_TOT * K_DIM;
        if (real_only) {
            build_wc_kernel<<<256, 256, 0, stream>>>(wcos, Wb);   // rows k=0..511
            dft_gemm_half<<<256, 512, 0, stream>>>(x, Wb, out);
        } else {
            cvt_x_kernel<<<2048, 256, 0, stream>>>(x, xb);
            build_w_kernel<<<512, 256, 0, stream>>>(wsin, wcos, Wb);
            dft_gemm128<2048><<<128 * 16, 256, 0, stream>>>(xb, Wb, out, (long long)out_size);
        }
    } else {
        dft_naive<<<M_TOT, 256, 0, stream>>>(x, wsin, wcos, out, (long long)out_size,
                                             real_only);
    }
}

// Round 13
// 40.155 us; speedup vs baseline: 1.4625x; 1.0062x over previous
//
#include <hip/hip_runtime.h>
#include <stdint.h>

#define K_DIM 1024
#define M_TOT 16384
#define BM 128
#define BN 128
#define BK 64

typedef __attribute__((ext_vector_type(8))) short bf16x8;
typedef __attribute__((ext_vector_type(4))) float f32x4;
typedef __attribute__((ext_vector_type(8))) unsigned short u16x8;

__device__ inline uint16_t f2bf(float f) {
    union { float f; uint32_t u; } v; v.f = f;
    return (uint16_t)((v.u + 0x7fffu + ((v.u >> 16) & 1u)) >> 16);
}

// ---- x (16M f32) -> bf16 (only used by the 2048 fallback path) ----
__global__ void cvt_x_kernel(const float* __restrict__ x, uint16_t* __restrict__ xb) {
    const size_t n8 = (size_t)M_TOT * K_DIM / 8;
    for (size_t i = (size_t)blockIdx.x * blockDim.x + threadIdx.x; i < n8;
         i += (size_t)gridDim.x * blockDim.x) {
        const float4* s = (const float4*)x + i * 2;
        float4 a = s[0], b = s[1];
        u16x8 v;
        v[0] = f2bf(a.x); v[1] = f2bf(a.y); v[2] = f2bf(a.z); v[3] = f2bf(a.w);
        v[4] = f2bf(b.x); v[5] = f2bf(b.y); v[6] = f2bf(b.z); v[7] = f2bf(b.w);
        *(u16x8*)(xb + i * 8) = v;
    }
}

// ---- quarter weights: W[k][s] = cos(2*pi*k*s/1024), k,s in [0,512) ----
__global__ void build_wq_kernel(const float* __restrict__ wcos, uint16_t* __restrict__ W) {
    int i = blockIdx.x * blockDim.x + threadIdx.x;   // 32768 threads
    int k = i >> 6;            // 512 rows
    int sc = (i & 63) * 8;     // cols 0..511
    const float4* c = (const float4*)(wcos + (size_t)k * K_DIM + sc);
    float4 c0 = c[0], c1 = c[1];
    u16x8 vc;
    vc[0] = f2bf(c0.x); vc[1] = f2bf(c0.y); vc[2] = f2bf(c0.z); vc[3] = f2bf(c0.w);
    vc[4] = f2bf(c1.x); vc[5] = f2bf(c1.y); vc[6] = f2bf(c1.z); vc[7] = f2bf(c1.w);
    *(u16x8*)(W + (size_t)k * 512 + sc) = vc;
}

// ---- interleaved weights (fallback path): W[2k][s]=cos, W[2k+1][s]=-sin ----
__global__ void build_w_kernel(const float* __restrict__ wsin, const float* __restrict__ wcos,
                               uint16_t* __restrict__ W) {
    int i = blockIdx.x * blockDim.x + threadIdx.x;
    int k = i >> 7;
    int sc = (i & 127) * 8;
    const float4* c = (const float4*)(wcos + (size_t)k * K_DIM + sc);
    const float4* s = (const float4*)(wsin + (size_t)k * K_DIM + sc);
    float4 c0 = c[0], c1 = c[1], s0 = s[0], s1 = s[1];
    u16x8 vc, vs;
    vc[0] = f2bf(c0.x); vc[1] = f2bf(c0.y); vc[2] = f2bf(c0.z); vc[3] = f2bf(c0.w);
    vc[4] = f2bf(c1.x); vc[5] = f2bf(c1.y); vc[6] = f2bf(c1.z); vc[7] = f2bf(c1.w);
    vs[0] = f2bf(-s0.x); vs[1] = f2bf(-s0.y); vs[2] = f2bf(-s0.z); vs[3] = f2bf(-s0.w);
    vs[4] = f2bf(-s1.x); vs[5] = f2bf(-s1.y); vs[6] = f2bf(-s1.z); vs[7] = f2bf(-s1.w);
    *(u16x8*)(W + (size_t)(2 * k) * K_DIM + sc) = vc;
    *(u16x8*)(W + (size_t)(2 * k + 1) * K_DIM + sc) = vs;
}

// =====================================================================
// DOUBLE-SYMMETRY (k-fold + s-fold) fused bf16 MFMA GEMM.
//   out[m][k] = sum_s x[m][s] cos(2*pi*k*s/1024).
//   cos even in k: out[:,1024-k] == out[:,k]  -> compute k in [0,512).
//   cos even in s: fold input y[m,s] = x[m,s] + x[m,1024-s] (s>=1),
//     y[m,0]=x[m,0]; then out[m,k] = sum_{s<512} y cos + (-1)^k x[m,512].
//   GEMM: 16384 x 512 x 512 (1/4 the original FLOPs).
//   A-staging fuses the fold: fwd f32 loads + aligned mirror-window loads
//   (base 1016-S0, 16B-aligned; s==0 scalar select-guarded) -> f32 add ->
//   cvt_pk -> swizzled ds_write.  (-1)^k x512 added in the epilogue
//   (sign = lr&1, lane-uniform); k=512 col via signed-y reduce + x512.
//   Machinery from R9/R12: slot^(row&7) both-sides swizzle (0 conflicts),
//   B via global_load_lds pre-swizzled source, 1 barrier per K-tile,
//   counted boundary vmcnt(10) (drains B(kt+1); A(kt+2) stays in flight).
// =====================================================================
__global__ __launch_bounds__(512) void dft_gemm_quarter(const float* __restrict__ X,
                                                        const uint16_t* __restrict__ Bw,
                                                        float* __restrict__ C) {
    constexpr int NKT = 8;                    // K = 512, BK = 64
    __shared__ uint16_t lds[2][24576];        // per buf: A[128*64] @0, B[256*64] @elem 8192
    __shared__ float x512s[128];

    const int t = threadIdx.x;
    const int l = t & 63;
    const int wid = t >> 6;
    const int wr = wid >> 2;      // 0..1  (64-row half)
    const int wc = wid & 3;       // 0..3  (64-col quarter)
    const int lr = l & 15;
    const int lhi = l >> 4;
    const int xr7 = lr & 7;

    // T1: bijective XCD swizzle (nwg = 256, %8==0)
    int bid = blockIdx.x;
    {
        int nwg = gridDim.x;
        if ((nwg & 7) == 0) { int q = nwg >> 3; bid = (bid & 7) * q + (bid >> 3); }
    }
    const int bm = (bid >> 1) * 128;      // pairs (2m,2m+1) share A-panel, same XCD
    const int bn256 = (bid & 1) * 256;    // GEMM k-columns [bn256, bn256+256)

    // staging: rows r0, r0+64; slot sl (8 elems = 16 B)
    const int r0 = t >> 3, sl = t & 7;
    const int swsl = sl ^ (r0 & 7);
    const float* gA0 = X + (size_t)(bm + r0) * K_DIM + sl * 8;            // fwd f32 src
    const float* gM0 = X + (size_t)(bm + r0) * K_DIM + (1016 - sl * 8);   // mirror window base
    const int wA0 = (r0 * 8 + swsl) * 16;                                  // swz LDS byte (A)
    const uint16_t* gB0 = Bw + (size_t)(bn256 + r0) * 512 + swsl * 8;      // pre-swz src
    const int ldsB0 = 16384 + (t & ~63) * 16;                              // B byte base

    float4 ra[2][2], rm[2][2];     // in-flight fwd / mirror f32 (one K-tile)
    float rsv[2];                  // mirror scalar x[1024-S0]
    bool zf = false;               // staged tile has S0==0 (s=0 -> mirror 0)
    float nyq[2] = {0.f, 0.f};

    auto loadA_all = [&](int kt) {
        const int k0 = kt * 64;
        const int S0 = k0 + sl * 8;
#pragma unroll
        for (int i = 0; i < 2; ++i) {
            const float* pf = gA0 + (size_t)i * 64 * K_DIM + k0;
            ra[i][0] = *(const float4*)pf;
            ra[i][1] = *(const float4*)(pf + 4);
            const float* pm = gM0 + (size_t)i * 64 * K_DIM - k0;   // row*1024 + 1016-S0
            rm[i][0] = *(const float4*)pm;
            rm[i][1] = *(const float4*)(pm + 4);
            rsv[i] = pm[(S0 == 0) ? 0 : 8];                        // safe dummy at S0==0
        }
        zf = (S0 == 0);
    };
    auto stageB_all = [&](int d, int kt) {
        const int k0 = kt * 64;
#pragma unroll
        for (int i = 0; i < 4; ++i)
            __builtin_amdgcn_global_load_lds(
                (const __attribute__((address_space(1))) void*)(gB0 + (size_t)i * 64 * 512 + k0),
                (__attribute__((address_space(3))) void*)((char*)&lds[d][0] + ldsB0 + i * 8192),
                16, 0, 0);
    };
    auto writeA_all = [&](int d, bool donyq) {
#pragma unroll
        for (int i = 0; i < 2; ++i) {
            float y0 = ra[i][0].x + (zf ? 0.f : rsv[i]);
            float y1 = ra[i][0].y + rm[i][1].w;
            float y2 = ra[i][0].z + rm[i][1].z;
            float y3 = ra[i][0].w + rm[i][1].y;
            float y4 = ra[i][1].x + rm[i][1].x;
            float y5 = ra[i][1].y + rm[i][0].w;
            float y6 = ra[i][1].z + rm[i][0].z;
            float y7 = ra[i][1].w + rm[i][0].y;
            union { u16x8 v; uint32_t u32[4]; } u;
            asm("v_cvt_pk_bf16_f32 %0, %1, %2" : "=v"(u.u32[0]) : "v"(y0), "v"(y1));
            asm("v_cvt_pk_bf16_f32 %0, %1, %2" : "=v"(u.u32[1]) : "v"(y2), "v"(y3));
            asm("v_cvt_pk_bf16_f32 %0, %1, %2" : "=v"(u.u32[2]) : "v"(y4), "v"(y5));
            asm("v_cvt_pk_bf16_f32 %0, %1, %2" : "=v"(u.u32[3]) : "v"(y6), "v"(y7));
            *(u16x8*)((char*)&lds[d][0] + wA0 + i * 8192) = u.v;
            if (donyq)   // sign (-1)^(S0+j) = (-1)^j
                nyq[i] += (y0 - y1) + (y2 - y3) + (y4 - y5) + (y6 - y7);
        }
    };
    // swizzled fragment read: element = row*64 + ((slot ^ (row&7))*8)
    auto loadFrag = [&](const uint16_t* buf, int row, int kk) -> bf16x8 {
        int s = (kk >> 3) + lhi;
        return *(const bf16x8*)(buf + row * 64 + ((s ^ xr7) * 8));
    };

    f32x4 acc[4][4] = {};

    // ---- prologue ----
    loadA_all(0);                            // 10 VMEM (oldest)
    stageB_all(0, 0);                        // 4 VMEM
    __builtin_amdgcn_sched_barrier(0);
    writeA_all(0, true);                     // compiler waits A(0); publishes tile 0
    __builtin_amdgcn_sched_barrier(0);
    loadA_all(1);                            // 10 VMEM
    __builtin_amdgcn_sched_barrier(0);
    asm volatile("s_waitcnt vmcnt(10)" ::: "memory");   // B(0) landed; A(1) in flight
    asm volatile("s_waitcnt lgkmcnt(0)" ::: "memory");
    __builtin_amdgcn_s_barrier();
    __builtin_amdgcn_sched_barrier(0);

    // ---- main loop: one barrier per K-tile ----
    for (int kt = 0; kt < NKT; ++kt) {
        const int cc = kt & 1;
        const uint16_t* bA = &lds[cc][0];
        const uint16_t* bB = &lds[cc][8192];
        int ktn = kt + 1;  if (ktn >= NKT) ktn -= NKT;    // wrap: uniform counts
        int ktnn = kt + 2; if (ktnn >= NKT) ktnn -= NKT;

        // publish A(kt+1) -> buf[1-cc] (nyq-guarded vs wrap); issue B(kt+1), A(kt+2)
        writeA_all(1 - cc, kt + 1 < NKT);
        __builtin_amdgcn_sched_barrier(0);
        stageB_all(1 - cc, ktn);
        loadA_all(ktnn);
        __builtin_amdgcn_sched_barrier(0);

        // compute on buf[cc]: 16 ds_read_b128 + 32 MFMA
#pragma unroll
        for (int ks = 0; ks < 2; ++ks) {
            const int kk = ks * 32;
            bf16x8 bfr[4], af[4];
#pragma unroll
            for (int n = 0; n < 4; ++n) bfr[n] = loadFrag(bB, wc * 64 + n * 16 + lr, kk);
#pragma unroll
            for (int m = 0; m < 4; ++m) af[m] = loadFrag(bA, wr * 64 + m * 16 + lr, kk);
            __builtin_amdgcn_s_setprio(1);
#pragma unroll
            for (int m = 0; m < 4; ++m)
#pragma unroll
                for (int n = 0; n < 4; ++n)
                    acc[m][n] = __builtin_amdgcn_mfma_f32_16x16x32_bf16(af[m], bfr[n],
                                                                        acc[m][n], 0, 0, 0);
            __builtin_amdgcn_s_setprio(0);
        }

        // boundary: B(kt+1) landed (14 outstanding -> 10); A(kt+2) stays in flight
        __builtin_amdgcn_sched_barrier(0);
        asm volatile("s_waitcnt vmcnt(10)" ::: "memory");
        asm volatile("s_waitcnt lgkmcnt(0)" ::: "memory");
        __builtin_amdgcn_s_barrier();
        __builtin_amdgcn_sched_barrier(0);
    }

    // ---- x512 row-vector + Nyquist reduce ----
    float xv = 0.f;
    if (t < 128) xv = X[(size_t)(bm + t) * K_DIM + 512];
    float* nl = (float*)&lds[0][0];          // 1024 f32 (4 KB), loop is done
    nl[r0 * 8 + sl] = nyq[0];
    nl[(64 + r0) * 8 + sl] = nyq[1];
    if (t < 128) x512s[t] = xv;
    __syncthreads();
    if (t < 128 && bn256 == 0) {
        float s = 0.f;
#pragma unroll
        for (int j = 0; j < 8; ++j) s += nl[t * 8 + j];
        C[(size_t)(bm + t) * 1024 + 512] = s + x512s[t];
    }

    // ---- epilogue: v = acc + (-1)^k x512; straight col k + mirror 1024-k ----
    const int cr = lhi * 4;
    const float sg = (lr & 1) ? -1.f : 1.f;   // col parity == lr&1 (others even)
#pragma unroll
    for (int m = 0; m < 4; ++m) {
#pragma unroll
        for (int j = 0; j < 4; ++j) {
            int rowL = wr * 64 + m * 16 + cr + j;
            float corr = sg * x512s[rowL];
            size_t base = (size_t)(bm + rowL) * 1024;
#pragma unroll
            for (int n = 0; n < 4; ++n) {
                int col = bn256 + wc * 64 + n * 16 + lr;
                float v = acc[m][n][j] + corr;
                C[base + col] = v;
                if (col) C[base + 1024 - col] = v;   // k=0 has no mirror
            }
        }
    }
}

// ---- 128x128 gload_lds GEMM (fallback for the interleaved/2048 path) ----
template <int NDIM>
__global__ __launch_bounds__(256) void dft_gemm128(const uint16_t* __restrict__ A,
                                                   const uint16_t* __restrict__ B,
                                                   float* __restrict__ C,
                                                   long long out_elems) {
    constexpr int NT = NDIM / BN;
    __shared__ uint16_t As[BM * BK];
    __shared__ uint16_t Bs[BN * BK];

    const int t = threadIdx.x;
    const int l = t & 63;
    const int w = t >> 6;

    int bid = blockIdx.x;
    {
        int nwg = gridDim.x;
        if ((nwg & 7) == 0) { int q = nwg >> 3; bid = (bid & 7) * q + (bid >> 3); }
    }
    const int bm = (bid / NT) * BM;
    const int bn = (bid % NT) * BN;

    const uint16_t* gA[4];
    const uint16_t* gB[4];
    int ldsOff[4];
#pragma unroll
    for (int i = 0; i < 4; ++i) {
        int chunk = i * 256 + t;
        int row = chunk >> 3;
        int cc = (chunk & 7) * 8;
        gA[i] = A + (size_t)(bm + row) * K_DIM + cc;
        gB[i] = B + (size_t)(bn + row) * K_DIM + cc;
        ldsOff[i] = (i * 256 + (t & 192)) * 16;
    }

    const int wm = ((w >> 1) & 1) * 64;
    const int wn = (w & 1) * 64;
    const int lr = l & 15;
    const int lk = (l >> 4) * 8;

    f32x4 acc[4][4] = {};

    for (int k0 = 0; k0 < K_DIM; k0 += BK) {
#pragma unroll
        for (int i = 0; i < 4; ++i)
            __builtin_amdgcn_global_load_lds(
                (const __attribute__((address_space(1))) void*)(gA[i] + k0),
                (__attribute__((address_space(3))) void*)((char*)As + ldsOff[i]), 16, 0, 0);
#pragma unroll
        for (int i = 0; i < 4; ++i)
            __builtin_amdgcn_global_load_lds(
                (const __attribute__((address_space(1))) void*)(gB[i] + k0),
                (__attribute__((address_space(3))) void*)((char*)Bs + ldsOff[i]), 16, 0, 0);
        __syncthreads();
#pragma unroll
        for (int kk = 0; kk < BK; kk += 32) {
            bf16x8 af[4], bfr[4];
#pragma unroll
            for (int m = 0; m < 4; ++m)
                af[m] = *(const bf16x8*)&As[(wm + m * 16 + lr) * BK + kk + lk];
#pragma unroll
            for (int n = 0; n < 4; ++n)
                bfr[n] = *(const bf16x8*)&Bs[(wn + n * 16 + lr) * BK + kk + lk];
#pragma unroll
            for (int m = 0; m < 4; ++m)
#pragma unroll
                for (int n = 0; n < 4; ++n)
                    acc[m][n] = __builtin_amdgcn_mfma_f32_16x16x32_bf16(af[m], bfr[n],
                                                                        acc[m][n], 0, 0, 0);
        }
        __syncthreads();
    }

    const int cr = (l >> 4) * 4;
    const bool safe = ((long long)(bm + BM) * NDIM) <= out_elems;
    if (safe) {
#pragma unroll
        for (int m = 0; m < 4; ++m) {
            int grow = bm + wm + m * 16 + cr;
#pragma unroll
            for (int j = 0; j < 4; ++j) {
                float* cp = C + (size_t)(grow + j) * NDIM + bn + wn + lr;
#pragma unroll
                for (int n = 0; n < 4; ++n)
                    cp[n * 16] = acc[m][n][j];
            }
        }
    } else {
        for (int m = 0; m < 4; ++m) {
            int grow = bm + wm + m * 16 + cr;
            for (int j = 0; j < 4; ++j) {
                long long base = (long long)(grow + j) * NDIM + bn + wn + lr;
                for (int n = 0; n < 4; ++n)
                    if (base + n * 16 < out_elems) C[base + n * 16] = acc[m][n][j];
            }
        }
    }
}

// ---- fp32 fallback (only if ws too small) ----
__global__ void dft_naive(const float* __restrict__ x, const float* __restrict__ wsin,
                          const float* __restrict__ wcos, float* __restrict__ out,
                          long long out_elems, int real_only) {
    __shared__ float xs[K_DIM];
    int row = blockIdx.x;
    const float* xr = x + (size_t)row * K_DIM;
    for (int i = threadIdx.x; i < K_DIM; i += blockDim.x) xs[i] = xr[i];
    __syncthreads();
    for (int k = threadIdx.x; k < K_DIM; k += blockDim.x) {
        const float* wc = wcos + (size_t)k * K_DIM;
        float re = 0.f;
        if (real_only) {
            for (int s = 0; s < K_DIM; ++s) re += xs[s] * wc[s];
            long long o = (long long)row * K_DIM + k;
            if (o < out_elems) out[o] = re;
        } else {
            const float* ws = wsin + (size_t)k * K_DIM;
            float im = 0.f;
            for (int s = 0; s < K_DIM; ++s) { re += xs[s] * wc[s]; im += xs[s] * ws[s]; }
            long long o = ((long long)row * K_DIM + k) * 2;
            if (o + 1 < out_elems) { out[o] = re; out[o + 1] = -im; }
        }
    }
}

extern "C" void kernel_launch(void* const* d_in, const int* in_sizes, int n_in,
                              void* d_out, int out_size, void* d_ws, size_t ws_size,
                              hipStream_t stream) {
    const float* x    = (const float*)d_in[0];
    const float* wsin = (const float*)d_in[1];
    const float* wcos = (const float*)d_in[2];
    float* out = (float*)d_out;

    const int real_only = (out_size == M_TOT * 1024);
    const size_t need = (size_t)M_TOT * K_DIM * 2 + (size_t)2048 * K_DIM * 2;

    if (ws_size >= need) {
        uint16_t* xb = (uint16_t*)d_ws;
        uint16_t* Wb = xb + (size_t)M_TOT * K_DIM;
        if (real_only) {
            build_wq_kernel<<<128, 256, 0, stream>>>(wcos, Wb);   // 512x512 quarter-W
            dft_gemm_quarter<<<256, 512, 0, stream>>>(x, Wb, out);
        } else {
            cvt_x_kernel<<<2048, 256, 0, stream>>>(x, xb);
            build_w_kernel<<<512, 256, 0, stream>>>(wsin, wcos, Wb);
            dft_gemm128<2048><<<128 * 16, 256, 0, stream>>>(xb, Wb, out, (long long)out_size);
        }
    } else {
        dft_naive<<<M_TOT, 256, 0, stream>>>(x, wsin, wcos, out, (long long)out_size,
                                             real_only);
    }
}